// Round 1
// 519.192 us; speedup vs baseline: 1.1000x; 1.1000x over previous
//
#include <hip/hip_runtime.h>

#define M_DIM 8192
#define K_DIM 2048
#define N_DIM 5632

typedef __attribute__((ext_vector_type(8))) short short8;
typedef __attribute__((ext_vector_type(4))) float f32x4;

// fp32 -> bf16 round-to-nearest-even (bit trick; inputs are finite)
__device__ __forceinline__ short f2b(float f) {
  union { float f; unsigned u; } v; v.f = f;
  unsigned r = v.u + 0x7FFFu + ((v.u >> 16) & 1u);
  return (short)(r >> 16);
}

// async global->LDS, 16B per lane. LDS dest must be wave-uniform base + lane*16.
__device__ __forceinline__ void async16(void* lds, const void* g) {
  __builtin_amdgcn_global_load_lds(
      (const __attribute__((address_space(1))) unsigned*)g,
      (__attribute__((address_space(3))) unsigned*)lds,
      16, 0, 0);
}

// ---------------- Kernel 1: x fp32 -> bf16 -----------------------------------
__global__ __launch_bounds__(256) void cvt_x_kernel(const float* __restrict__ x,
                                                    short* __restrict__ xb) {
  long t = (long)blockIdx.x * 256 + threadIdx.x;   // 8 elements per thread
  const float4* xv = (const float4*)x;
  float4 f0 = xv[2 * t];
  float4 f1 = xv[2 * t + 1];
  short8 o;
  o[0] = f2b(f0.x); o[1] = f2b(f0.y); o[2] = f2b(f0.z); o[3] = f2b(f0.w);
  o[4] = f2b(f1.x); o[5] = f2b(f1.y); o[6] = f2b(f1.z); o[7] = f2b(f1.w);
  *(short8*)(xb + 8 * t) = o;
}

// ---------------- Kernel 2: dequant int4 + fold rank-16 LoRA into W' ---------
// W'[o][i] = (q - zero[g]) * scale[g] + 2 * sum_r A[i][r] * B[r][o]
__global__ __launch_bounds__(256) void dequant_lora_kernel(
    const int* __restrict__ packed, const float* __restrict__ scales,
    const float* __restrict__ zeros, const float* __restrict__ lA,
    const float* __restrict__ lB, short* __restrict__ wb) {
  int o = blockIdx.x;
  int i0 = threadIdx.x * 8;                  // first of 8 W elements in row o
  long e0 = (long)o * K_DIM + i0;            // flat W index
  int4 p = ((const int4*)packed)[e0 >> 3];   // 4 packed bytes -> 8 codes
  int g = (int)(e0 >> 7);                    // group of 128 (8 | 128, same group)
  float s = scales[g], z = zeros[g];

  // B column for this o, pre-scaled by lora 2.0 (uniform per block)
  float bcol[16];
#pragma unroll
  for (int r = 0; r < 16; ++r) bcol[r] = lB[r * N_DIM + o] * 2.0f;

  short8 out8;
#pragma unroll
  for (int d = 0; d < 4; ++d) {
    int pv = (&p.x)[d];                      // two nibbles
    float w0 = ((float)(pv & 0xF) - z) * s;        // element e0+2d   (low)
    float w1 = ((float)((pv >> 4) & 0xF) - z) * s; // element e0+2d+1 (high)
    const float4* a0 = (const float4*)&lA[(i0 + 2 * d) * 16];
    const float4* a1 = (const float4*)&lA[(i0 + 2 * d + 1) * 16];
    float acc0 = 0.f, acc1 = 0.f;
#pragma unroll
    for (int r4 = 0; r4 < 4; ++r4) {
      float4 av0 = a0[r4], av1 = a1[r4];
      acc0 += av0.x * bcol[4 * r4] + av0.y * bcol[4 * r4 + 1] +
              av0.z * bcol[4 * r4 + 2] + av0.w * bcol[4 * r4 + 3];
      acc1 += av1.x * bcol[4 * r4] + av1.y * bcol[4 * r4 + 1] +
              av1.z * bcol[4 * r4 + 2] + av1.w * bcol[4 * r4 + 3];
    }
    out8[2 * d] = f2b(w0 + acc0);
    out8[2 * d + 1] = f2b(w1 + acc1);
  }
  *(short8*)(wb + e0) = out8;
}

// ---------------- Kernel 3: C[m][n] = sum_k X[m][k] * W'[n][k] ---------------
// 256x256 tile, BK=32, 8 waves (2Mx4N), per-wave 128x64 = acc[8][4].
// LDS: 4-deep K-tile ring (A:4x16KB, B:4x16KB = 128KB). Prefetch distance 3;
// tile-end wait = counted vmcnt(8) (2 tiles in flight), never 0 in main loop.
// Swizzle: LDS slot s of row r holds global 16B-chunk s ^ ((r>>1)&3)
//   -> ds_read_b128 banks: (16*(r&1) + 4*(q^((r>>1)&3)))%32 = 2-way only (free).
__global__ __launch_bounds__(512, 2) void gemm_kernel(const short* __restrict__ xb,
                                                      const short* __restrict__ wb,
                                                      float* __restrict__ out) {
  // [0,32768): A bufs (4 x 8192 shorts), [32768,65536): B bufs
  __shared__ __align__(16) short lds[65536];   // 128 KB

  const int tid = threadIdx.x;
  const int lane = tid & 63;
  const int wave = tid >> 6;
  const int wm = wave >> 2, wn = wave & 3;     // 2(M) x 4(N) wave grid
  const int l15 = lane & 15, quad = lane >> 4;

  // XCD-aware bijective swizzle: 704 blocks = 8 XCDs x 88
  int flat = blockIdx.x;
  int swz = (flat & 7) * 88 + (flat >> 3);
  int bm = swz / 22, bn = swz - bm * 22;
  const int m0 = bm * 256, n0 = bn * 256;

  const short* a_base = xb + (size_t)m0 * K_DIM;
  const short* b_base = wb + (size_t)n0 * K_DIM;

  // LDS read offsets (shorts). Row base is a multiple of 16, so
  // (row>>1)&3 == (l15>>1)&3 for every fragment row.
  const int rswz = quad ^ ((l15 >> 1) & 3);
  const int a_rd = (wm * 128 + l15) * 32 + rswz * 8;           // + mi*512 + buf
  const int b_rd = 32768 + (wn * 64 + l15) * 32 + rswz * 8;    // + ni*512 + buf

  // Staging: 4 x global_load_lds(16B)/thread/tile. gi = it*512+tid covers
  // row = gi>>2, slot = gi&3; source chunk = slot ^ ((row>>1)&3) (inverse swz).
  const int srow = tid >> 2;
  const int schunk = (tid & 3) ^ ((srow >> 1) & 3);  // same for srow+128 (128%4==0 after >>1 ... (64)&3==0)
  const short* ag0 = a_base + (size_t)srow * K_DIM + schunk * 8;
  const short* ag1 = ag0 + (size_t)128 * K_DIM;
  const short* bg0 = b_base + (size_t)srow * K_DIM + schunk * 8;
  const short* bg1 = bg0 + (size_t)128 * K_DIM;
  const int sl0 = tid * 8, sl1 = (512 + tid) * 8;    // linear LDS dest (shorts)

  f32x4 acc[8][4] = {};

  // Prologue: stage K-tiles 0,1,2 into bufs 0,1,2 (12 loads); wait tile 0 only.
#pragma unroll
  for (int t = 0; t < 3; ++t) {
    const int sb = t * 8192;
    async16(&lds[sb + sl0], ag0 + t * 32);
    async16(&lds[sb + sl1], ag1 + t * 32);
    async16(&lds[32768 + sb + sl0], bg0 + t * 32);
    async16(&lds[32768 + sb + sl1], bg1 + t * 32);
  }
  asm volatile("s_waitcnt vmcnt(8)" ::: "memory");
  __builtin_amdgcn_s_barrier();

  // One K-tile = 2 phases x {ds_read subtile, stage half of tile k+3,
  // barrier, setprio(1) 16 MFMA setprio(0), barrier}.
  auto tile = [&](int k, bool do_stage) {
    const int bo = (k & 3) * 8192;         // compute buffer
    const int so = ((k + 3) & 3) * 8192;   // stage target (freed after tile k-1)
    short8 bf[4], af[4];
#pragma unroll
    for (int ni = 0; ni < 4; ++ni)
      bf[ni] = *(const short8*)&lds[bo + b_rd + ni * 512];
#pragma unroll
    for (int mi = 0; mi < 4; ++mi)
      af[mi] = *(const short8*)&lds[bo + a_rd + mi * 512];
    if (do_stage) {
      async16(&lds[so + sl0], ag0 + (k + 3) * 32);
      async16(&lds[so + sl1], ag1 + (k + 3) * 32);
    }
    __builtin_amdgcn_s_barrier();
    __builtin_amdgcn_s_setprio(1);
#pragma unroll
    for (int mi = 0; mi < 4; ++mi)
#pragma unroll
      for (int ni = 0; ni < 4; ++ni)
        acc[mi][ni] = __builtin_amdgcn_mfma_f32_16x16x32_bf16(
            af[mi], bf[ni], acc[mi][ni], 0, 0, 0);
    __builtin_amdgcn_s_setprio(0);
    __builtin_amdgcn_s_barrier();
    // phase 2: rows 64..127 of the wave's A panel; bf reused from registers
#pragma unroll
    for (int mi = 0; mi < 4; ++mi)
      af[mi] = *(const short8*)&lds[bo + a_rd + (4 + mi) * 512];
    if (do_stage) {
      async16(&lds[32768 + so + sl0], bg0 + (k + 3) * 32);
      async16(&lds[32768 + so + sl1], bg1 + (k + 3) * 32);
    }
    __builtin_amdgcn_s_barrier();
    __builtin_amdgcn_s_setprio(1);
#pragma unroll
    for (int mi = 0; mi < 4; ++mi)
#pragma unroll
      for (int ni = 0; ni < 4; ++ni)
        acc[4 + mi][ni] = __builtin_amdgcn_mfma_f32_16x16x32_bf16(
            af[mi], bf[ni], acc[4 + mi][ni], 0, 0, 0);
    __builtin_amdgcn_s_setprio(0);
  };

  // Main loop: tiles 0..60 stage tile k+3 (3..63). Tile-end fence is the
  // counted vmcnt + raw barrier ("memory" clobber = the ordering point that
  // keeps ds_reads/stage-issues from crossing tile boundaries).
#pragma unroll 1
  for (int k = 0; k < 61; ++k) {
    tile(k, true);
    asm volatile("s_waitcnt vmcnt(8)" ::: "memory");  // tile k+1 resident; k+2,k+3 in flight
    __builtin_amdgcn_s_barrier();
  }
  tile(61, false);
  asm volatile("s_waitcnt vmcnt(4)" ::: "memory");    // tile 62 resident
  __builtin_amdgcn_s_barrier();
  tile(62, false);
  asm volatile("s_waitcnt vmcnt(0)" ::: "memory");    // tile 63 resident
  __builtin_amdgcn_s_barrier();
  tile(63, false);

  // Epilogue: C/D layout col = lane&15, row = quad*4 + reg  [m89-verified]
  float* op = out + (size_t)(m0 + wm * 128 + quad * 4) * N_DIM + n0 + wn * 64 + l15;
#pragma unroll
  for (int mi = 0; mi < 8; ++mi)
#pragma unroll
    for (int r = 0; r < 4; ++r)
#pragma unroll
      for (int ni = 0; ni < 4; ++ni)
        op[(size_t)(mi * 16 + r) * N_DIM + ni * 16] = acc[mi][ni][r];
}

// -----------------------------------------------------------------------------
extern "C" void kernel_launch(void* const* d_in, const int* in_sizes, int n_in,
                              void* d_out, int out_size, void* d_ws, size_t ws_size,
                              hipStream_t stream) {
  const float* x      = (const float*)d_in[0];  // [4,2048,2048] fp32
  const int*   packed = (const int*)d_in[1];    // [5767168] int32 (byte values)
  const float* scales = (const float*)d_in[2];  // [90112]
  const float* zeros  = (const float*)d_in[3];  // [90112]
  const float* lA     = (const float*)d_in[4];  // [2048,16]
  const float* lB     = (const float*)d_in[5];  // [16,5632]
  float* out = (float*)d_out;                   // [4,2048,5632] fp32

  short* xb = (short*)d_ws;                     // x in bf16: 16,777,216 shorts
  short* wb = xb + (size_t)M_DIM * K_DIM;       // W' in bf16: 11,534,336 shorts

  cvt_x_kernel<<<(M_DIM * K_DIM) / (256 * 8), 256, 0, stream>>>(x, xb);
  dequant_lora_kernel<<<N_DIM, 256, 0, stream>>>(packed, scales, zeros, lA, lB, wb);
  gemm_kernel<<<dim3(N_DIM / 256 * (M_DIM / 256)), 512, 0, stream>>>(xb, wb, out);
}